// Round 1
// 4686.596 us; speedup vs baseline: 1.0261x; 1.0261x over previous
//
#include <hip/hip_runtime.h>
#include <cmath>

constexpr int SEQ = 64;    // sequence length
constexpr int NB  = 128;   // batch
constexpr int H   = 256;   // hidden
constexpr int DIN = 128;   // composed token dim
constexpr int DE  = 256;   // word emb dim
constexpr int NA  = 64;    // actions
constexpr int S1  = 41;    // STACK_SIZE+1
constexpr int MS  = 100;   // max steps
constexpr int G4  = 1024;  // 4*H

__device__ __forceinline__ float sigf(float x){ return 1.0f/(1.0f+expf(-x)); }

// ---------------- transpose: in [R][C] -> out [C][R]
__global__ void transpose_k(const float* __restrict__ in, float* __restrict__ out,
                            int R, int C){
  __shared__ float t[32][33];
  int bx = blockIdx.x*32, by = blockIdx.y*32;
  int x = threadIdx.x, y = threadIdx.y;   // block 32x8
  #pragma unroll
  for (int j = 0; j < 32; j += 8)
    t[y+j][x] = in[(size_t)(by+y+j)*C + bx + x];
  __syncthreads();
  #pragma unroll
  for (int j = 0; j < 32; j += 8)
    out[(size_t)(bx+y+j)*R + by + x] = t[x][y+j];
}

// hist_xz[a][r] = hist_Wih[r,:] . action_emb[a,:] + hist_bih[r] + hist_bhh[r]
__global__ void hist_proj_kernel(const float* __restrict__ Wih,
                                 const float* __restrict__ bih,
                                 const float* __restrict__ bhh,
                                 const float* __restrict__ aemb,
                                 float* __restrict__ out){
  int a = blockIdx.x, t = threadIdx.x;
  __shared__ float e[64];
  if (t < 64) e[t] = aemb[a*64 + t];
  __syncthreads();
  for (int r = t; r < G4; r += blockDim.x){
    const float* w = Wih + r*64;
    float acc = bih[r] + bhh[r];
    #pragma unroll
    for (int k = 0; k < 64; k += 4)
      acc += w[k]*e[k] + w[k+1]*e[k+1] + w[k+2]*e[k+2] + w[k+3]*e[k+3];
    out[a*G4 + r] = acc;
  }
}

// One workgroup per batch element; 1024 threads (16 waves -> 4/SIMD).
// All matvecs read TRANSPOSED weights with float4 lane-contiguous loads and
// deep c-splits; partials are reduced through LDS. f64 accumulation kept on
// the argmax-critical summary/logits path.
__global__ __launch_bounds__(1024, 1)
void parser_kernel(const int* __restrict__ tokens,
                   const float* __restrict__ word_emb,
                   const float* __restrict__ Wt_cmp,   // [256][128]
                   const float* __restrict__ compose_b,
                   const float* __restrict__ h0,
                   const float* __restrict__ c0,
                   const float* __restrict__ Wt_pbih,  // [128][1024]
                   const float* __restrict__ Wt_pb,    // [256][1024]
                   const float* __restrict__ pb_bih,
                   const float* __restrict__ pb_bhh,
                   const float* __restrict__ Wt_stih,  // [128][1024]
                   const float* __restrict__ Wt_st,    // [256][1024]
                   const float* __restrict__ st_bih,
                   const float* __restrict__ st_bhh,
                   const float* __restrict__ Wt_hi,    // [256][1024]
                   const float* __restrict__ Wt_sum,   // [768][256]
                   const float* __restrict__ sum_b,
                   const float* __restrict__ Wt_act,   // [256][64]
                   const float* __restrict__ act_b,
                   const int* __restrict__ stack_map,
                   const int* __restrict__ buffer_map,
                   const float* __restrict__ histxz,   // [64][1024]
                   float* __restrict__ pb_zx,   // [B][64][1024]
                   float* __restrict__ st_zx,   // [B][65][1024] (row 64 = bias only)
                   float* __restrict__ bufh,    // [B][64][256]
                   float* __restrict__ scst,    // [B][41][256] stack c
                   float* __restrict__ out)     // [100][128][64]
{
  __shared__ __align__(16) float u0[12288];  // P0: tok[64][128]+emb[16][256]; main: stack_h[41][256]
  __shared__ __align__(16) float u1[8192];   // partial buffers (B: 4096 f64; D/P1: 4x1024 f32; C: 512 f64 @ +6144)
  __shared__ __align__(16) float bstate[H];
  __shared__ __align__(16) float ahl[H];
  __shared__ __align__(16) float acl[H];
  __shared__ __align__(16) float h0l[H];
  __shared__ __align__(16) float summ[H];
  __shared__ int ctl[12];

  const int b   = blockIdx.x;
  const int tid = threadIdx.x;

  float* tokl   = u0;              // [64][128]
  float* embs   = u0 + SEQ*DIN;    // [16][256]
  float* stackh = u0;              // [41][256]

  if (tid < H) h0l[tid] = h0[tid];
  __syncthreads();

  // ---------------- P0a: tok[t] = relu(W_c @ emb[tokens[t,b]] + b_c)
  {
    const int d = tid & 127, tb = tid >> 7;   // tb 0..7, 2 tokens each
    const float cb = compose_b[d];
    for (int pass = 0; pass < 4; ++pass){
      for (int j = tid >> 8; j < 16; j += 4){
        int tt = pass*16 + j;
        int id = tokens[tt*NB + b];
        embs[j*DE + (tid & 255)] = word_emb[(size_t)id*DE + (tid & 255)];
      }
      __syncthreads();
      float a0 = 0.f, a1 = 0.f;
      const float* eb = embs + (tb*2)*DE;
      for (int c = 0; c < DE; ++c){
        float w = Wt_cmp[c*DIN + d];
        a0 += w*eb[c]; a1 += w*eb[DE + c];
      }
      int t0 = pass*16 + tb*2;
      tokl[(t0    )*DIN + d] = fmaxf(a0 + cb, 0.f);
      tokl[(t0 + 1)*DIN + d] = fmaxf(a1 + cb, 0.f);
      __syncthreads();   // embs reads done before next pass restages
    }
  }

  // ---------------- P0b: zx = Wih @ tok + (bih+bhh).  m=0: pb (tid<512), m=1: st.
  {
    const int m  = tid >> 9;
    const int lt = tid & 255;          // float4 quad over 1024 rows
    const int sub = (tid >> 8) & 1;    // token half of each 16-token blk
    const float* Wt  = m ? Wt_stih : Wt_pbih;           // [128][1024]
    float*       zxb = m ? (st_zx + (size_t)b*(SEQ+1)*G4) : (pb_zx + (size_t)b*SEQ*G4);
    const float* bA  = m ? st_bih : pb_bih;
    const float* bB  = m ? st_bhh : pb_bhh;
    float4 x1 = ((const float4*)bA)[lt], x2 = ((const float4*)bB)[lt];
    float bx = x1.x + x2.x, by = x1.y + x2.y, bz = x1.z + x2.z, bw = x1.w + x2.w;
    for (int blk = 0; blk < 4; ++blk){
      float ax[8], ay[8], az[8], aw[8];
      #pragma unroll
      for (int t = 0; t < 8; ++t){ ax[t]=0.f; ay[t]=0.f; az[t]=0.f; aw[t]=0.f; }
      const float* tb = tokl + (blk*16 + sub*8)*DIN;
      for (int c = 0; c < DIN; ++c){
        float4 w = ((const float4*)(Wt + (size_t)c*G4))[lt];
        #pragma unroll
        for (int t = 0; t < 8; ++t){
          float x = tb[t*DIN + c];
          ax[t] += w.x*x; ay[t] += w.y*x; az[t] += w.z*x; aw[t] += w.w*x;
        }
      }
      #pragma unroll
      for (int t = 0; t < 8; ++t){
        float4 r = make_float4(ax[t]+bx, ay[t]+by, az[t]+bz, aw[t]+bw);
        ((float4*)(zxb + (size_t)(blk*16 + sub*8 + t)*G4))[lt] = r;
      }
    }
    if (m == 1 && sub == 0)
      ((float4*)(zxb + (size_t)SEQ*G4))[lt] = make_float4(bx, by, bz, bw);
  }
  __syncthreads();

  // ---------------- P1: pre-buffer LSTM over reversed tokens
  // 4-way c-split x float4 row-quads: 64 loads/thread/round, LDS partial reduce.
  if (tid < H){ ahl[tid] = h0l[tid]; acl[tid] = c0[tid]; }   // (h,c)
  __syncthreads();
  for (int k = 0; k < SEQ; ++k){
    const int tt = SEQ - 1 - k;
    {
      const int q = tid & 255, cg = tid >> 8;   // cg 0..3
      float a0=0.f, a1=0.f, a2=0.f, a3=0.f;
      const int cb2 = cg*64;
      for (int c = cb2; c < cb2 + 64; ++c){
        float4 w = ((const float4*)(Wt_pb + (size_t)c*G4))[q];
        float x = ahl[c];
        a0 += w.x*x; a1 += w.y*x; a2 += w.z*x; a3 += w.w*x;
      }
      ((float4*)(u1 + cg*G4))[q] = make_float4(a0, a1, a2, a3);
    }
    __syncthreads();
    if (tid < H){
      const float* zx = pb_zx + ((size_t)b*SEQ + tt)*G4;
      float zi_ = u1[tid]     + u1[G4+tid]     + u1[2*G4+tid]     + u1[3*G4+tid]     + zx[tid];
      float zf_ = u1[H+tid]   + u1[G4+H+tid]   + u1[2*G4+H+tid]   + u1[3*G4+H+tid]   + zx[H+tid];
      float zg_ = u1[2*H+tid] + u1[G4+2*H+tid] + u1[2*G4+2*H+tid] + u1[3*G4+2*H+tid] + zx[2*H+tid];
      float zo_ = u1[3*H+tid] + u1[G4+3*H+tid] + u1[2*G4+3*H+tid] + u1[3*G4+3*H+tid] + zx[3*H+tid];
      float c2 = sigf(zf_)*acl[tid] + sigf(zi_)*tanhf(zg_);
      float h2 = sigf(zo_)*tanhf(c2);
      acl[tid] = c2; ahl[tid] = h2;
      bufh[((size_t)b*SEQ + k)*H + tid] = h2;
    }
    __syncthreads();
  }

  // ---------------- main init
  for (int i = tid; i < S1*H; i += 1024) stackh[i] = 0.f;
  if (tid < H) bstate[tid] = ahl[tid];          // b_state = buf_h[63]
  __syncthreads();
  if (tid < H) stackh[tid] = h0l[tid];          // stack_h[0] = h0
  {
    float* cst = scst + (size_t)b*S1*H;
    for (int i = tid; i < S1*H; i += 1024) cst[i] = (i < H) ? c0[i] : 0.f;
  }
  if (tid < H){ ahl[tid] = h0l[tid]; acl[tid] = c0[tid]; }   // hist LSTM state
  if (tid == 0){ ctl[0] = 0; ctl[1] = SEQ; ctl[2] = SEQ - 1; } // spos, bpos, sin_idx
  __syncthreads();

  // ---------------- main parser loop
  for (int step = 0; step < MS; ++step){
    const int spos = ctl[0], bposc = ctl[1], sinc = ctl[2];

    // B: summary partials, f64, 16-way c-split (48 c each), float4 row-quads
    {
      const int lt = tid & 63, cg = tid >> 6;   // rows 4lt..4lt+3, cg 0..15
      double a0=0.0, a1=0.0, a2=0.0, a3=0.0;
      const int cbeg = cg*48, cend = cbeg + 48;
      for (int c = cbeg; c < cend; ++c){
        float4 w = ((const float4*)(Wt_sum + (size_t)c*H))[lt];
        float xc = (c < 256) ? stackh[spos*H + c]
                 : (c < 512) ? bstate[c - 256] : ahl[c - 512];
        double dx = (double)xc;
        a0 += (double)w.x*dx; a1 += (double)w.y*dx;
        a2 += (double)w.z*dx; a3 += (double)w.w*dx;
      }
      double* pd = (double*)u1;
      pd[cg*256 + lt*4    ] = a0;
      pd[cg*256 + lt*4 + 1] = a1;
      pd[cg*256 + lt*4 + 2] = a2;
      pd[cg*256 + lt*4 + 3] = a3;
    }
    __syncthreads();
    if (tid < H){
      const double* pd = (const double*)u1;
      double s = (double)sum_b[tid];
      #pragma unroll
      for (int g = 0; g < 16; ++g) s += pd[g*256 + tid];
      summ[tid] = fmaxf((float)s, 0.f);
    }
    __syncthreads();

    // C partials: 8-way c-split over threads 0-511, f64 (region u1+6144 floats)
    if (tid < 512){
      const int o = tid & 63, cg = tid >> 6;
      double acc = 0.0;
      const int cb2 = cg*32;
      for (int c = cb2; c < cb2 + 32; ++c)
        acc += (double)Wt_act[c*NA + o] * (double)summ[c];
      ((double*)(u1 + 6144))[cg*64 + o] = acc;
    }
    __syncthreads();

    // merged phase: wave 0 finalizes C (logits/softmax/argmax/control),
    // then joins D. D partials need only PREVIOUS-step state, so they hide C.
    if (tid < 64){
      const double* pc = (const double*)(u1 + 6144);
      double acc = (double)act_b[tid];
      #pragma unroll
      for (int g = 0; g < 8; ++g) acc += pc[g*64 + tid];
      float v = (float)acc;
      float mx = v;
      #pragma unroll
      for (int o = 32; o > 0; o >>= 1) mx = fmaxf(mx, __shfl_xor(mx, o));
      float ex = expf(v - mx), sm = ex;
      #pragma unroll
      for (int o = 32; o > 0; o >>= 1) sm += __shfl_xor(sm, o);
      out[(((size_t)step*NB) + b)*NA + tid] = v - mx - logf(sm);
      float bv = v; int bi = tid;     // argmax, first index wins on ties
      #pragma unroll
      for (int o = 32; o > 0; o >>= 1){
        float ov = __shfl_xor(bv, o); int oi = __shfl_xor(bi, o);
        if (ov > bv || (ov == bv && oi < bi)){ bv = ov; bi = oi; }
      }
      if (tid == 0){
        int a = bi;
        int sop = stack_map[a], bop = buffer_map[a];
        if (spos == 0 && sop == -1) sop = 0;
        if (spos >= S1 - 1 && sop == 1) sop = 0;
        if (bposc == 0 && bop == -1) bop = 0;
        int push  = (sop == 1) ? 1 : 0;
        int widx  = (spos + 1 < S1 - 1) ? spos + 1 : S1 - 1;
        int sposn = spos + sop;
        int bposn = bposc + bop;
        int ne    = (bposn > 0) ? 1 : 0;
        int gidx  = bposn - 1; if (gidx < 0) gidx = 0; if (gidx > SEQ - 1) gidx = SEQ - 1;
        ctl[3] = a; ctl[4] = push; ctl[5] = widx; ctl[6] = sposn;
        ctl[7] = bposn; ctl[8] = ne; ctl[9] = gidx;
      }
    }
    // D partials: both z-vectors across all 1024 threads, 2-way c-split (128 c)
    {
      const int zi = tid >> 9;           // 0 = st, 1 = hist
      const int q  = tid & 255;          // float4 quad over 1024 rows
      const int cg = (tid >> 8) & 1;     // c half
      const float* Wt = zi ? Wt_hi : Wt_st;                 // [256][1024]
      const float* xv = zi ? ahl : (stackh + spos*H);
      float a0=0.f, a1=0.f, a2=0.f, a3=0.f;
      const int cb3 = cg*128;
      for (int c = cb3; c < cb3 + 128; ++c){
        float4 w = ((const float4*)(Wt + (size_t)c*G4))[q];
        float x = xv[c];
        a0 += w.x*x; a1 += w.y*x; a2 += w.z*x; a3 += w.w*x;
      }
      ((float4*)(u1 + (zi*2 + cg)*G4))[q] = make_float4(a0, a1, a2, a3);
    }
    __syncthreads();

    // E: gates + state commit (biases gathered here; st uses sinc, hist uses a)
    {
      const int a = ctl[3], push = ctl[4], widx = ctl[5], sposn = ctl[6];
      const int ne = ctl[8], gidx = ctl[9];
      if (tid < H){
        const float* zb = st_zx + ((size_t)b*(SEQ+1) + sinc)*G4;
        float zi_ = u1[tid]     + u1[G4+tid]     + zb[tid];
        float zf_ = u1[H+tid]   + u1[G4+H+tid]   + zb[H+tid];
        float zg_ = u1[2*H+tid] + u1[G4+2*H+tid] + zb[2*H+tid];
        float zo_ = u1[3*H+tid] + u1[G4+3*H+tid] + zb[3*H+tid];
        float ctop = scst[((size_t)b*S1 + spos)*H + tid];
        float c2 = sigf(zf_)*ctop + sigf(zi_)*tanhf(zg_);
        float h2 = sigf(zo_)*tanhf(c2);
        if (push){
          stackh[widx*H + tid] = h2;
          scst[((size_t)b*S1 + widx)*H + tid] = c2;
        }
        bstate[tid] = ne ? bufh[((size_t)b*SEQ + gidx)*H + tid] : h0l[tid];
      } else if (tid < 2*H){
        const int hh = tid - H;
        const float* hb = histxz + (size_t)a*G4;
        float zi_ = u1[2*G4+hh]     + u1[3*G4+hh]     + hb[hh];
        float zf_ = u1[2*G4+H+hh]   + u1[3*G4+H+hh]   + hb[H+hh];
        float zg_ = u1[2*G4+2*H+hh] + u1[3*G4+2*H+hh] + hb[2*H+hh];
        float zo_ = u1[2*G4+3*H+hh] + u1[3*G4+3*H+hh] + hb[3*H+hh];
        float c2 = sigf(zf_)*acl[hh] + sigf(zi_)*tanhf(zg_);
        float h2 = sigf(zo_)*tanhf(c2);
        acl[hh] = c2; ahl[hh] = h2;
      }
      if (tid == 0){
        ctl[0] = sposn; ctl[1] = ctl[7]; ctl[2] = ne ? gidx : SEQ;
      }
    }
    __syncthreads();
  }
}

extern "C" void kernel_launch(void* const* d_in, const int* in_sizes, int n_in,
                              void* d_out, int out_size, void* d_ws, size_t ws_size,
                              hipStream_t stream){
  (void)in_sizes; (void)n_in; (void)out_size; (void)ws_size;
  const int*   tokens    = (const int*)  d_in[0];
  const float* word_emb  = (const float*)d_in[1];
  const float* compose_W = (const float*)d_in[2];
  const float* compose_b = (const float*)d_in[3];
  const float* h0        = (const float*)d_in[4];
  const float* c0        = (const float*)d_in[5];
  const float* pb_Wih    = (const float*)d_in[6];
  const float* pb_Whh    = (const float*)d_in[7];
  const float* pb_bih    = (const float*)d_in[8];
  const float* pb_bhh    = (const float*)d_in[9];
  const float* st_Wih    = (const float*)d_in[10];
  const float* st_Whh    = (const float*)d_in[11];
  const float* st_bih    = (const float*)d_in[12];
  const float* st_bhh    = (const float*)d_in[13];
  const float* hist_Wih  = (const float*)d_in[14];
  const float* hist_Whh  = (const float*)d_in[15];
  const float* hist_bih  = (const float*)d_in[16];
  const float* hist_bhh  = (const float*)d_in[17];
  const float* sum_W     = (const float*)d_in[18];
  const float* sum_b     = (const float*)d_in[19];
  const float* act_W     = (const float*)d_in[20];
  const float* act_b     = (const float*)d_in[21];
  const float* action_emb= (const float*)d_in[22];
  const int*   stack_map = (const int*)  d_in[23];
  const int*   buffer_map= (const int*)  d_in[24];

  float* ws     = (float*)d_ws;
  float* pb_zx  = ws;                                  // 128*64*1024
  float* st_zx  = pb_zx + (size_t)NB*SEQ*G4;           // 128*65*1024
  float* bufh   = st_zx + (size_t)NB*(SEQ+1)*G4;       // 128*64*256
  float* scst   = bufh  + (size_t)NB*SEQ*H;            // 128*41*256
  float* histxz = scst  + (size_t)NB*S1*H;             // 64*1024
  float* Wt_pb  = histxz + (size_t)NA*G4;              // [256][1024]
  float* Wt_st  = Wt_pb  + (size_t)H*G4;
  float* Wt_hi  = Wt_st  + (size_t)H*G4;
  float* Wt_sum = Wt_hi  + (size_t)H*G4;               // [768][256]
  float* Wt_act = Wt_sum + (size_t)768*H;              // [256][64]
  float* Wt_pbih= Wt_act + (size_t)H*NA;               // [128][1024]
  float* Wt_stih= Wt_pbih+ (size_t)DIN*G4;             // [128][1024]
  float* Wt_cmp = Wt_stih+ (size_t)DIN*G4;             // [256][128]

  dim3 blk(32, 8);
  transpose_k<<<dim3(256/32, 1024/32), blk, 0, stream>>>(pb_Whh,   Wt_pb,  1024, 256);
  transpose_k<<<dim3(256/32, 1024/32), blk, 0, stream>>>(st_Whh,   Wt_st,  1024, 256);
  transpose_k<<<dim3(256/32, 1024/32), blk, 0, stream>>>(hist_Whh, Wt_hi,  1024, 256);
  transpose_k<<<dim3(768/32,  256/32), blk, 0, stream>>>(sum_W,    Wt_sum,  256, 768);
  transpose_k<<<dim3(256/32,   64/32), blk, 0, stream>>>(act_W,    Wt_act,   64, 256);
  transpose_k<<<dim3(128/32, 1024/32), blk, 0, stream>>>(pb_Wih,   Wt_pbih,1024, 128);
  transpose_k<<<dim3(128/32, 1024/32), blk, 0, stream>>>(st_Wih,   Wt_stih,1024, 128);
  transpose_k<<<dim3(256/32,  128/32), blk, 0, stream>>>(compose_W,Wt_cmp,  128, 256);
  hist_proj_kernel<<<dim3(NA), dim3(256), 0, stream>>>(hist_Wih, hist_bih, hist_bhh,
                                                       action_emb, histxz);

  parser_kernel<<<dim3(NB), dim3(1024), 0, stream>>>(tokens, word_emb, Wt_cmp, compose_b,
      h0, c0, Wt_pbih, Wt_pb, pb_bih, pb_bhh, Wt_stih, Wt_st, st_bih, st_bhh,
      Wt_hi, Wt_sum, sum_b, Wt_act, act_b, stack_map, buffer_map,
      histxz, pb_zx, st_zx, bufh, scst, (float*)d_out);
}